// Round 7
// baseline (661.574 us; speedup 1.0000x reference)
//
#include <hip/hip_runtime.h>

#define D 64
#define LAYERS 3
#define BSHIFT 8                 // bucket = dst >> 8 (256 nodes per bucket)
#define NBMAX 512                // max buckets supported (N <= 131072)
#define CHUNK 4096               // edges per pass-1 block (256 thr x 16)
#define WSTRIDE 72               // padded LDS row stride (ushorts)
#define DBINS 128                // degree bins for node balancing

typedef unsigned short ushort_t;
typedef __bf16 bf16x8 __attribute__((ext_vector_type(8)));
typedef float f32x4 __attribute__((ext_vector_type(4)));

__device__ __forceinline__ ushort_t f2bf(float f) {           // RNE float->bf16
    unsigned b = __float_as_uint(f);
    b += 0x7FFFu + ((b >> 16) & 1u);
    return (ushort_t)(b >> 16);
}
__device__ __forceinline__ float bflo(unsigned u) { return __uint_as_float(u << 16); }
__device__ __forceinline__ float bfhi(unsigned u) { return __uint_as_float(u & 0xFFFF0000u); }

// ---------------- projections via MFMA ----------------
__global__ __launch_bounds__(256) void proj_kernel(
    const float* __restrict__ x,
    const float* __restrict__ Wq, const float* __restrict__ bq,
    const float* __restrict__ Wk, const float* __restrict__ bk,
    const float* __restrict__ Wv, const float* __restrict__ bv,
    const float* __restrict__ Ws, const float* __restrict__ bs,
    float* __restrict__ q, ushort_t* __restrict__ kv,
    float* __restrict__ hout, int N)
{
    __shared__ ushort_t xs[32 * WSTRIDE];
    __shared__ ushort_t wt[4 * 64 * WSTRIDE];

    const int t = threadIdx.x;
    const int block_row = blockIdx.x * 32;

    {   // stage x tile (fp32 -> bf16)
        const int r  = t >> 3;
        const int c8 = (t & 7) * 8;
        const int row = block_row + r;
        float4 x0, x1;
        if (row < N) {
            x0 = *(const float4*)(x + (size_t)row * D + c8);
            x1 = *(const float4*)(x + (size_t)row * D + c8 + 4);
        } else {
            x0 = make_float4(0.f,0.f,0.f,0.f); x1 = x0;
        }
        uint4 u;
        u.x = (unsigned)f2bf(x0.x) | ((unsigned)f2bf(x0.y) << 16);
        u.y = (unsigned)f2bf(x0.z) | ((unsigned)f2bf(x0.w) << 16);
        u.z = (unsigned)f2bf(x1.x) | ((unsigned)f2bf(x1.y) << 16);
        u.w = (unsigned)f2bf(x1.z) | ((unsigned)f2bf(x1.w) << 16);
        *(uint4*)(xs + r * WSTRIDE + c8) = u;
    }
    {   // stage W^T (fp32 -> bf16): wt[m][n*WSTRIDE+k] = W_m[k*64+n]
        const float* Wm[4] = {Wq, Wk, Wv, Ws};
#pragma unroll
        for (int m = 0; m < 4; ++m) {
            const float* W = Wm[m];
            ushort_t* wtm = wt + m * 64 * WSTRIDE;
#pragma unroll
            for (int i = 0; i < 16; ++i) {
                const int e = i * 256 + t;
                const int k = e >> 6, n = e & 63;
                wtm[n * WSTRIDE + k] = f2bf(W[e]);
            }
        }
    }
    __syncthreads();

    const int l  = t & 63;
    const int w  = t >> 6;            // wave id: 0=q,1=k,2=v,3=skip
    const int lr = l & 15;
    const int lk = (l >> 4) * 8;

    bf16x8 afr[2][2];
#pragma unroll
    for (int rt = 0; rt < 2; ++rt)
#pragma unroll
        for (int ks = 0; ks < 2; ++ks)
            afr[rt][ks] = *(const bf16x8*)(xs + (rt*16 + lr) * WSTRIDE + ks*32 + lk);

    const ushort_t* wtw = wt + w * 64 * WSTRIDE;
    f32x4 acc[2][4];
#pragma unroll
    for (int rt = 0; rt < 2; ++rt)
#pragma unroll
        for (int ct = 0; ct < 4; ++ct)
            acc[rt][ct] = (f32x4){0.f, 0.f, 0.f, 0.f};

#pragma unroll
    for (int ct = 0; ct < 4; ++ct) {
        const bf16x8 b0 = *(const bf16x8*)(wtw + (ct*16 + lr) * WSTRIDE + lk);
        const bf16x8 b1 = *(const bf16x8*)(wtw + (ct*16 + lr) * WSTRIDE + 32 + lk);
        acc[0][ct] = __builtin_amdgcn_mfma_f32_16x16x32_bf16(afr[0][0], b0, acc[0][ct], 0, 0, 0);
        acc[0][ct] = __builtin_amdgcn_mfma_f32_16x16x32_bf16(afr[0][1], b1, acc[0][ct], 0, 0, 0);
        acc[1][ct] = __builtin_amdgcn_mfma_f32_16x16x32_bf16(afr[1][0], b0, acc[1][ct], 0, 0, 0);
        acc[1][ct] = __builtin_amdgcn_mfma_f32_16x16x32_bf16(afr[1][1], b1, acc[1][ct], 0, 0, 0);
    }

    const float* biasW = (w == 0) ? bq : (w == 1) ? bk : (w == 2) ? bv : bs;
    float bcol[4];
#pragma unroll
    for (int ct = 0; ct < 4; ++ct) bcol[ct] = biasW[ct*16 + lr];

#pragma unroll
    for (int rt = 0; rt < 2; ++rt) {
#pragma unroll
        for (int ct = 0; ct < 4; ++ct) {
#pragma unroll
            for (int r = 0; r < 4; ++r) {
                const int row = block_row + rt*16 + (l >> 4) * 4 + r;
                const int col = ct*16 + lr;
                if (row < N) {
                    const float val = acc[rt][ct][r] + bcol[ct];
                    if (w == 0)      q[(size_t)row * D + col]    = val;
                    else if (w == 3) hout[(size_t)row * D + col] = val;
                    else {
                        ushort_t* kvr = kv + (size_t)row * 128;
                        kvr[(col >> 2) * 8 + ((w == 2) ? 4 : 0) + (col & 3)] = f2bf(val);
                    }
                }
            }
        }
    }
}

// ---------------- two-pass bucketed counting sort ----------------
__global__ __launch_bounds__(256) void b_hist_kernel(
    const int* __restrict__ dst, int* __restrict__ bcount, int E)
{
    __shared__ int h[NBMAX];
    const int t = threadIdx.x;
    h[t] = 0; h[t + 256] = 0;
    __syncthreads();
    const int base = blockIdx.x * CHUNK;
#pragma unroll
    for (int i = 0; i < 16; ++i) {
        const int e = base + i * 256 + t;
        if (e < E) atomicAdd(h + (dst[e] >> BSHIFT), 1);
    }
    __syncthreads();
    if (h[t])       atomicAdd(bcount + t, h[t]);
    if (h[t + 256]) atomicAdd(bcount + t + 256, h[t + 256]);
}

__global__ __launch_bounds__(512) void b_scan_kernel(
    const int* __restrict__ bcount, int* __restrict__ bbase,
    int* __restrict__ gcursor, int E)
{
    __shared__ int tmp[NBMAX];
    const int t = threadIdx.x;
    const int val = bcount[t];
    tmp[t] = val;
    __syncthreads();
    for (int off = 1; off < NBMAX; off <<= 1) {
        int x = (t >= off) ? tmp[t - off] : 0;
        __syncthreads();
        tmp[t] += x;
        __syncthreads();
    }
    const int excl = tmp[t] - val;
    bbase[t] = excl;
    gcursor[t] = excl;
    if (t == NBMAX - 1) bbase[NBMAX] = E;
}

__global__ __launch_bounds__(256) void b_scatter_kernel(
    const int* __restrict__ src, const int* __restrict__ dst,
    int* __restrict__ gcursor, uint2* __restrict__ packed, int E)
{
    __shared__ int h[NBMAX];
    __shared__ int gb[NBMAX];
    const int t = threadIdx.x;
    h[t] = 0; h[t + 256] = 0;
    __syncthreads();

    const int base = blockIdx.x * CHUNK;
    int ls[16], ld[16], lr[16];
#pragma unroll
    for (int i = 0; i < 16; ++i) {
        const int e = base + i * 256 + t;
        if (e < E) {
            ls[i] = src[e];
            ld[i] = dst[e];
            lr[i] = atomicAdd(h + (ld[i] >> BSHIFT), 1);
        }
    }
    __syncthreads();
    for (int b = t; b < NBMAX; b += 256) {
        const int c = h[b];
        gb[b] = c ? atomicAdd(gcursor + b, c) : 0;
    }
    __syncthreads();
#pragma unroll
    for (int i = 0; i < 16; ++i) {
        const int e = base + i * 256 + t;
        if (e < E) {
            const int pos = gb[ld[i] >> BSHIFT] + lr[i];
            packed[pos] = make_uint2((unsigned)ls[i], (unsigned)ld[i]);
        }
    }
}

__global__ __launch_bounds__(256) void b_final_kernel(
    const uint2* __restrict__ packed, const int* __restrict__ bbase,
    int* __restrict__ esrc, int* __restrict__ offs, int* __restrict__ counts,
    int N)
{
    __shared__ int hist[256];
    __shared__ int scan[256];
    __shared__ int cursor[256];
    const int t = threadIdx.x;
    const int b = blockIdx.x;
    const int s = bbase[b];
    const int e = bbase[b + 1];

    hist[t] = 0;
    __syncthreads();
    for (int j = s + t; j < e; j += 256) {
        atomicAdd(hist + (packed[j].y & 255), 1);
    }
    __syncthreads();
    const int val = hist[t];
    scan[t] = val;
    __syncthreads();
    for (int off = 1; off < 256; off <<= 1) {
        int x = (t >= off) ? scan[t - off] : 0;
        __syncthreads();
        scan[t] += x;
        __syncthreads();
    }
    const int excl = scan[t] - val;
    const int node = b * 256 + t;
    if (node < N) {
        counts[node] = val;
        offs[node]   = s + excl;
    }
    cursor[t] = excl;
    __syncthreads();
    for (int j = s + t; j < e; j += 256) {
        const uint2 p = packed[j];
        const int r = atomicAdd(cursor + (p.y & 255), 1);
        esrc[s + r] = (int)p.x;
    }
}

// ---------------- degree-balanced node permutation ----------------
__global__ __launch_bounds__(256) void deg_hist_kernel(
    const int* __restrict__ counts, int* __restrict__ dh, int N)
{
    __shared__ int h[DBINS];
    const int t = threadIdx.x;
    if (t < DBINS) h[t] = 0;
    __syncthreads();
    const int i = blockIdx.x * 256 + t;
    if (i < N) atomicAdd(h + min(counts[i], DBINS - 1), 1);
    __syncthreads();
    if (t < DBINS && h[t]) atomicAdd(dh + t, h[t]);
}

__global__ __launch_bounds__(DBINS) void deg_scan_kernel(
    const int* __restrict__ dh, int* __restrict__ dcur)
{
    __shared__ int tmp[DBINS];
    const int t = threadIdx.x;
    const int val = dh[t];
    tmp[t] = val;
    __syncthreads();
    for (int off = 1; off < DBINS; off <<= 1) {
        int x = (t >= off) ? tmp[t - off] : 0;
        __syncthreads();
        tmp[t] += x;
        __syncthreads();
    }
    dcur[t] = tmp[t] - val;        // exclusive
}

__global__ __launch_bounds__(256) void deg_scatter_kernel(
    const int* __restrict__ counts, int* __restrict__ dcur,
    int* __restrict__ perm, int N)
{
    const int i = blockIdx.x * 256 + threadIdx.x;
    if (i >= N) return;
    const int d = min(counts[i], DBINS - 1);
    const int pos = atomicAdd(dcur + d, 1);
    perm[pos] = i;
}

// ---------------- fused per-node attention ----------------
// 16 lanes/node; nodes taken in degree-sorted order via perm[] so the 4
// nodes sharing a wave have ~equal edge counts (no divergence waste).
__global__ __launch_bounds__(256) void node_kernel(
    const float* __restrict__ q, const uint4* __restrict__ kv,
    const int* __restrict__ esrc, const int* __restrict__ offs,
    const int* __restrict__ counts, const int* __restrict__ perm,
    float* __restrict__ hout, int N, int do_relu)
{
    const int t = threadIdx.x;
    const int lane = t & 15;
    const int idx = blockIdx.x * 16 + (t >> 4);
    if (idx >= N) return;
    const int node = perm[idx];

    const int start = offs[node];
    const int end   = start + counts[node];

    const float4 qv = *(const float4*)(q + (size_t)node * D + lane * 4);

    float m = -INFINITY, ssum = 0.0f;
    float4 acc = make_float4(0.0f, 0.0f, 0.0f, 0.0f);

    int j = start;
    for (; j + 2 <= end; j += 2) {
        const int s0 = esrc[j];
        const int s1 = esrc[j + 1];
        const uint4 u0 = kv[(size_t)s0 * 16 + lane];
        const uint4 u1 = kv[(size_t)s1 * 16 + lane];

        float p0 = bflo(u0.x) * qv.x + bfhi(u0.x) * qv.y
                 + bflo(u0.y) * qv.z + bfhi(u0.y) * qv.w;
        float p1 = bflo(u1.x) * qv.x + bfhi(u1.x) * qv.y
                 + bflo(u1.y) * qv.z + bfhi(u1.y) * qv.w;
        p0 += __shfl_xor(p0, 1);  p1 += __shfl_xor(p1, 1);
        p0 += __shfl_xor(p0, 2);  p1 += __shfl_xor(p1, 2);
        p0 += __shfl_xor(p0, 4);  p1 += __shfl_xor(p1, 4);
        p0 += __shfl_xor(p0, 8);  p1 += __shfl_xor(p1, 8);
        p0 *= 0.125f;  p1 *= 0.125f;

        const float mx = fmaxf(p0, p1);
        if (mx > m) {
            const float sc = __expf(m - mx);
            ssum *= sc;
            acc.x *= sc; acc.y *= sc; acc.z *= sc; acc.w *= sc;
            m = mx;
        }
        const float w0 = __expf(p0 - m);
        const float w1 = __expf(p1 - m);
        ssum += w0 + w1;
        acc.x = fmaf(w0, bflo(u0.z), fmaf(w1, bflo(u1.z), acc.x));
        acc.y = fmaf(w0, bfhi(u0.z), fmaf(w1, bfhi(u1.z), acc.y));
        acc.z = fmaf(w0, bflo(u0.w), fmaf(w1, bflo(u1.w), acc.z));
        acc.w = fmaf(w0, bfhi(u0.w), fmaf(w1, bfhi(u1.w), acc.w));
    }
    if (j < end) {
        const int s0 = esrc[j];
        const uint4 u0 = kv[(size_t)s0 * 16 + lane];
        float p0 = bflo(u0.x) * qv.x + bfhi(u0.x) * qv.y
                 + bflo(u0.y) * qv.z + bfhi(u0.y) * qv.w;
        p0 += __shfl_xor(p0, 1);
        p0 += __shfl_xor(p0, 2);
        p0 += __shfl_xor(p0, 4);
        p0 += __shfl_xor(p0, 8);
        p0 *= 0.125f;
        if (p0 > m) {
            const float sc = __expf(m - p0);
            ssum *= sc;
            acc.x *= sc; acc.y *= sc; acc.z *= sc; acc.w *= sc;
            m = p0;
        }
        const float w0 = __expf(p0 - m);
        ssum += w0;
        acc.x = fmaf(w0, bflo(u0.z), acc.x);
        acc.y = fmaf(w0, bfhi(u0.z), acc.y);
        acc.z = fmaf(w0, bflo(u0.w), acc.z);
        acc.w = fmaf(w0, bfhi(u0.w), acc.w);
    }

    const float inv = 1.0f / (ssum + 1e-16f);
    float* o = hout + (size_t)node * D + lane * 4;
    float4 ov = *(const float4*)o;
    ov.x = fmaf(acc.x, inv, ov.x);
    ov.y = fmaf(acc.y, inv, ov.y);
    ov.z = fmaf(acc.z, inv, ov.z);
    ov.w = fmaf(acc.w, inv, ov.w);
    if (do_relu) {
        ov.x = fmaxf(ov.x, 0.0f); ov.y = fmaxf(ov.y, 0.0f);
        ov.z = fmaxf(ov.z, 0.0f); ov.w = fmaxf(ov.w, 0.0f);
    }
    *(float4*)o = ov;
}

extern "C" void kernel_launch(void* const* d_in, const int* in_sizes, int n_in,
                              void* d_out, int out_size, void* d_ws, size_t ws_size,
                              hipStream_t stream)
{
    const float* x   = (const float*)d_in[0];
    const int* ei    = (const int*)d_in[1];
    const float* Wq  = (const float*)d_in[3];
    const float* bq  = (const float*)d_in[4];
    const float* Wk  = (const float*)d_in[5];
    const float* bk  = (const float*)d_in[6];
    const float* Wv  = (const float*)d_in[7];
    const float* bv  = (const float*)d_in[8];
    const float* Ws  = (const float*)d_in[9];
    const float* bs  = (const float*)d_in[10];

    const int N = in_sizes[0] / D;
    const int E = in_sizes[2];
    const int* src = ei;
    const int* dst = ei + E;
    const int NB = (N + 255) / 256;

    // workspace layout
    float* fws = (float*)d_ws;
    float* q     = fws;                             // N*D floats
    ushort_t* kv = (ushort_t*)(q + (size_t)N * D);  // N*128 bf16
    float* h0    = (float*)(kv + (size_t)N * 128);  // N*D
    float* h1    = h0 + (size_t)N * D;              // N*D
    int* esrc    = (int*)(h1 + (size_t)N * D);      // E
    uint2* packed = (uint2*)(esrc + E);             // E uint2
    int* counts  = (int*)(packed + E);              // NBMAX*256
    int* offs    = counts + NBMAX * 256;            // NBMAX*256
    int* bcount  = offs + NBMAX * 256;              // NBMAX
    int* bbase   = bcount + NBMAX;                  // NBMAX+1
    int* gcursor = bbase + NBMAX + 1;               // NBMAX
    int* perm    = gcursor + NBMAX;                 // N
    int* dh      = perm + N;                        // DBINS
    int* dcur    = dh + DBINS;                      // DBINS

    // ---- sort edges by dst + degree-balanced node order (once per call) ----
    hipMemsetAsync(bcount, 0, NBMAX * 4, stream);
    hipMemsetAsync(dh, 0, DBINS * 4, stream);
    const int p1_blocks = (E + CHUNK - 1) / CHUNK;
    b_hist_kernel<<<p1_blocks, 256, 0, stream>>>(dst, bcount, E);
    b_scan_kernel<<<1, NBMAX, 0, stream>>>(bcount, bbase, gcursor, E);
    b_scatter_kernel<<<p1_blocks, 256, 0, stream>>>(src, dst, gcursor, packed, E);
    b_final_kernel<<<NB, 256, 0, stream>>>(packed, bbase, esrc, offs, counts, N);
    deg_hist_kernel<<<(N + 255) / 256, 256, 0, stream>>>(counts, dh, N);
    deg_scan_kernel<<<1, DBINS, 0, stream>>>(dh, dcur);
    deg_scatter_kernel<<<(N + 255) / 256, 256, 0, stream>>>(counts, dcur, perm, N);

    const int proj_blocks = (N + 31) / 32;
    const int node_blocks = (N + 15) / 16;

    const float* cur = x;
    for (int l = 0; l < LAYERS; ++l) {
        float* hout = (l == LAYERS - 1) ? (float*)d_out : (l & 1 ? h1 : h0);

        proj_kernel<<<proj_blocks, 256, 0, stream>>>(
            cur,
            Wq + (size_t)l * D * D, bq + (size_t)l * D,
            Wk + (size_t)l * D * D, bk + (size_t)l * D,
            Wv + (size_t)l * D * D, bv + (size_t)l * D,
            Ws + (size_t)l * D * D, bs + (size_t)l * D,
            q, kv, hout, N);

        node_kernel<<<node_blocks, 256, 0, stream>>>(
            q, (const uint4*)kv, esrc, offs, counts, perm, hout, N,
            l < LAYERS - 1 ? 1 : 0);

        cur = hout;
    }
}

// Round 8
// 389.289 us; speedup vs baseline: 1.6994x; 1.6994x over previous
//
#include <hip/hip_runtime.h>

#define D 64
#define LAYERS 3
#define BSHIFT 8                 // bucket = dst >> 8 (256 nodes per bucket)
#define NBMAX 512                // max buckets supported (N <= 131072)
#define CHUNK 4096               // edges per pass-1 block (256 thr x 16)
#define WSTRIDE 72               // padded LDS row stride (ushorts)
#define DBINS 128                // degree bins for node balancing

typedef unsigned short ushort_t;
typedef __bf16 bf16x8 __attribute__((ext_vector_type(8)));
typedef float f32x4 __attribute__((ext_vector_type(4)));

__device__ __forceinline__ ushort_t f2bf(float f) {           // RNE float->bf16
    unsigned b = __float_as_uint(f);
    b += 0x7FFFu + ((b >> 16) & 1u);
    return (ushort_t)(b >> 16);
}
__device__ __forceinline__ float bflo(unsigned u) { return __uint_as_float(u << 16); }
__device__ __forceinline__ float bfhi(unsigned u) { return __uint_as_float(u & 0xFFFF0000u); }

// ---------------- projections via MFMA ----------------
__global__ __launch_bounds__(256) void proj_kernel(
    const float* __restrict__ x,
    const float* __restrict__ Wq, const float* __restrict__ bq,
    const float* __restrict__ Wk, const float* __restrict__ bk,
    const float* __restrict__ Wv, const float* __restrict__ bv,
    const float* __restrict__ Ws, const float* __restrict__ bs,
    float* __restrict__ q, ushort_t* __restrict__ kv,
    float* __restrict__ hout, int N)
{
    __shared__ ushort_t xs[32 * WSTRIDE];
    __shared__ ushort_t wt[4 * 64 * WSTRIDE];

    const int t = threadIdx.x;
    const int block_row = blockIdx.x * 32;

    {   // stage x tile (fp32 -> bf16)
        const int r  = t >> 3;
        const int c8 = (t & 7) * 8;
        const int row = block_row + r;
        float4 x0, x1;
        if (row < N) {
            x0 = *(const float4*)(x + (size_t)row * D + c8);
            x1 = *(const float4*)(x + (size_t)row * D + c8 + 4);
        } else {
            x0 = make_float4(0.f,0.f,0.f,0.f); x1 = x0;
        }
        uint4 u;
        u.x = (unsigned)f2bf(x0.x) | ((unsigned)f2bf(x0.y) << 16);
        u.y = (unsigned)f2bf(x0.z) | ((unsigned)f2bf(x0.w) << 16);
        u.z = (unsigned)f2bf(x1.x) | ((unsigned)f2bf(x1.y) << 16);
        u.w = (unsigned)f2bf(x1.z) | ((unsigned)f2bf(x1.w) << 16);
        *(uint4*)(xs + r * WSTRIDE + c8) = u;
    }
    {   // stage W^T (fp32 -> bf16): wt[m][n*WSTRIDE+k] = W_m[k*64+n]
        const float* Wm[4] = {Wq, Wk, Wv, Ws};
#pragma unroll
        for (int m = 0; m < 4; ++m) {
            const float* W = Wm[m];
            ushort_t* wtm = wt + m * 64 * WSTRIDE;
#pragma unroll
            for (int i = 0; i < 16; ++i) {
                const int e = i * 256 + t;
                const int k = e >> 6, n = e & 63;
                wtm[n * WSTRIDE + k] = f2bf(W[e]);
            }
        }
    }
    __syncthreads();

    const int l  = t & 63;
    const int w  = t >> 6;            // wave id: 0=q,1=k,2=v,3=skip
    const int lr = l & 15;
    const int lk = (l >> 4) * 8;

    bf16x8 afr[2][2];
#pragma unroll
    for (int rt = 0; rt < 2; ++rt)
#pragma unroll
        for (int ks = 0; ks < 2; ++ks)
            afr[rt][ks] = *(const bf16x8*)(xs + (rt*16 + lr) * WSTRIDE + ks*32 + lk);

    const ushort_t* wtw = wt + w * 64 * WSTRIDE;
    f32x4 acc[2][4];
#pragma unroll
    for (int rt = 0; rt < 2; ++rt)
#pragma unroll
        for (int ct = 0; ct < 4; ++ct)
            acc[rt][ct] = (f32x4){0.f, 0.f, 0.f, 0.f};

#pragma unroll
    for (int ct = 0; ct < 4; ++ct) {
        const bf16x8 b0 = *(const bf16x8*)(wtw + (ct*16 + lr) * WSTRIDE + lk);
        const bf16x8 b1 = *(const bf16x8*)(wtw + (ct*16 + lr) * WSTRIDE + 32 + lk);
        acc[0][ct] = __builtin_amdgcn_mfma_f32_16x16x32_bf16(afr[0][0], b0, acc[0][ct], 0, 0, 0);
        acc[0][ct] = __builtin_amdgcn_mfma_f32_16x16x32_bf16(afr[0][1], b1, acc[0][ct], 0, 0, 0);
        acc[1][ct] = __builtin_amdgcn_mfma_f32_16x16x32_bf16(afr[1][0], b0, acc[1][ct], 0, 0, 0);
        acc[1][ct] = __builtin_amdgcn_mfma_f32_16x16x32_bf16(afr[1][1], b1, acc[1][ct], 0, 0, 0);
    }

    const float* biasW = (w == 0) ? bq : (w == 1) ? bk : (w == 2) ? bv : bs;
    float bcol[4];
#pragma unroll
    for (int ct = 0; ct < 4; ++ct) bcol[ct] = biasW[ct*16 + lr];

#pragma unroll
    for (int rt = 0; rt < 2; ++rt) {
#pragma unroll
        for (int ct = 0; ct < 4; ++ct) {
#pragma unroll
            for (int r = 0; r < 4; ++r) {
                const int row = block_row + rt*16 + (l >> 4) * 4 + r;
                const int col = ct*16 + lr;
                if (row < N) {
                    const float val = acc[rt][ct][r] + bcol[ct];
                    if (w == 0)      q[(size_t)row * D + col]    = val;
                    else if (w == 3) hout[(size_t)row * D + col] = val;
                    else {
                        ushort_t* kvr = kv + (size_t)row * 128;
                        kvr[(col >> 2) * 8 + ((w == 2) ? 4 : 0) + (col & 3)] = f2bf(val);
                    }
                }
            }
        }
    }
}

// ---------------- two-pass bucketed counting sort ----------------
__global__ __launch_bounds__(256) void b_hist_kernel(
    const int* __restrict__ dst, int* __restrict__ bcount, int E)
{
    __shared__ int h[NBMAX];
    const int t = threadIdx.x;
    h[t] = 0; h[t + 256] = 0;
    __syncthreads();
    const int base = blockIdx.x * CHUNK;
#pragma unroll
    for (int i = 0; i < 16; ++i) {
        const int e = base + i * 256 + t;
        if (e < E) atomicAdd(h + (dst[e] >> BSHIFT), 1);
    }
    __syncthreads();
    if (h[t])       atomicAdd(bcount + t, h[t]);
    if (h[t + 256]) atomicAdd(bcount + t + 256, h[t + 256]);
}

__global__ __launch_bounds__(512) void b_scan_kernel(
    const int* __restrict__ bcount, int* __restrict__ bbase,
    int* __restrict__ gcursor, int E)
{
    __shared__ int tmp[NBMAX];
    const int t = threadIdx.x;
    const int val = bcount[t];
    tmp[t] = val;
    __syncthreads();
    for (int off = 1; off < NBMAX; off <<= 1) {
        int x = (t >= off) ? tmp[t - off] : 0;
        __syncthreads();
        tmp[t] += x;
        __syncthreads();
    }
    const int excl = tmp[t] - val;
    bbase[t] = excl;
    gcursor[t] = excl;
    if (t == NBMAX - 1) bbase[NBMAX] = E;
}

__global__ __launch_bounds__(256) void b_scatter_kernel(
    const int* __restrict__ src, const int* __restrict__ dst,
    int* __restrict__ gcursor, uint2* __restrict__ packed, int E)
{
    __shared__ int h[NBMAX];
    __shared__ int gb[NBMAX];
    const int t = threadIdx.x;
    h[t] = 0; h[t + 256] = 0;
    __syncthreads();

    const int base = blockIdx.x * CHUNK;
    int ls[16], ld[16], lr[16];
#pragma unroll
    for (int i = 0; i < 16; ++i) {
        const int e = base + i * 256 + t;
        if (e < E) {
            ls[i] = src[e];
            ld[i] = dst[e];
            lr[i] = atomicAdd(h + (ld[i] >> BSHIFT), 1);
        }
    }
    __syncthreads();
    for (int b = t; b < NBMAX; b += 256) {
        const int c = h[b];
        gb[b] = c ? atomicAdd(gcursor + b, c) : 0;
    }
    __syncthreads();
#pragma unroll
    for (int i = 0; i < 16; ++i) {
        const int e = base + i * 256 + t;
        if (e < E) {
            const int pos = gb[ld[i] >> BSHIFT] + lr[i];
            packed[pos] = make_uint2((unsigned)ls[i], (unsigned)ld[i]);
        }
    }
}

__global__ __launch_bounds__(256) void b_final_kernel(
    const uint2* __restrict__ packed, const int* __restrict__ bbase,
    int* __restrict__ esrc, int* __restrict__ offs, int* __restrict__ counts,
    int N)
{
    __shared__ int hist[256];
    __shared__ int scan[256];
    __shared__ int cursor[256];
    const int t = threadIdx.x;
    const int b = blockIdx.x;
    const int s = bbase[b];
    const int e = bbase[b + 1];

    hist[t] = 0;
    __syncthreads();
    for (int j = s + t; j < e; j += 256) {
        atomicAdd(hist + (packed[j].y & 255), 1);
    }
    __syncthreads();
    const int val = hist[t];
    scan[t] = val;
    __syncthreads();
    for (int off = 1; off < 256; off <<= 1) {
        int x = (t >= off) ? scan[t - off] : 0;
        __syncthreads();
        scan[t] += x;
        __syncthreads();
    }
    const int excl = scan[t] - val;
    const int node = b * 256 + t;
    if (node < N) {
        counts[node] = val;
        offs[node]   = s + excl;
    }
    cursor[t] = excl;
    __syncthreads();
    for (int j = s + t; j < e; j += 256) {
        const uint2 p = packed[j];
        const int r = atomicAdd(cursor + (p.y & 255), 1);
        esrc[s + r] = (int)p.x;
    }
}

// ---------------- degree-balanced node permutation ----------------
__global__ __launch_bounds__(256) void deg_hist_kernel(
    const int* __restrict__ counts, int* __restrict__ dh, int N)
{
    __shared__ int h[DBINS];
    const int t = threadIdx.x;
    if (t < DBINS) h[t] = 0;
    __syncthreads();
    const int i = blockIdx.x * 256 + t;
    if (i < N) atomicAdd(h + min(counts[i], DBINS - 1), 1);
    __syncthreads();
    if (t < DBINS && h[t]) atomicAdd(dh + t, h[t]);
}

__global__ __launch_bounds__(DBINS) void deg_scan_kernel(
    const int* __restrict__ dh, int* __restrict__ dcur)
{
    __shared__ int tmp[DBINS];
    const int t = threadIdx.x;
    const int val = dh[t];
    tmp[t] = val;
    __syncthreads();
    for (int off = 1; off < DBINS; off <<= 1) {
        int x = (t >= off) ? tmp[t - off] : 0;
        __syncthreads();
        tmp[t] += x;
        __syncthreads();
    }
    dcur[t] = tmp[t] - val;        // exclusive
}

// LDS-aggregated: one global atomic per (block,bin) instead of per node.
__global__ __launch_bounds__(256) void deg_scatter_kernel(
    const int* __restrict__ counts, int* __restrict__ dcur,
    int* __restrict__ perm, int N)
{
    __shared__ int h[DBINS];
    __shared__ int base[DBINS];
    const int t = threadIdx.x;
    if (t < DBINS) h[t] = 0;
    __syncthreads();
    const int i = blockIdx.x * 256 + t;
    int d = 0, lr = 0;
    const bool act = (i < N);
    if (act) {
        d = min(counts[i], DBINS - 1);
        lr = atomicAdd(h + d, 1);
    }
    __syncthreads();
    if (t < DBINS) {
        const int c = h[t];
        base[t] = c ? atomicAdd(dcur + t, c) : 0;
    }
    __syncthreads();
    if (act) perm[base[d] + lr] = i;
}

// ---------------- fused per-node attention ----------------
// 16 lanes/node; nodes taken in degree-sorted order via perm[] so the 4
// nodes sharing a wave have ~equal edge counts (no divergence waste).
__global__ __launch_bounds__(256) void node_kernel(
    const float* __restrict__ q, const uint4* __restrict__ kv,
    const int* __restrict__ esrc, const int* __restrict__ offs,
    const int* __restrict__ counts, const int* __restrict__ perm,
    float* __restrict__ hout, int N, int do_relu)
{
    const int t = threadIdx.x;
    const int lane = t & 15;
    const int idx = blockIdx.x * 16 + (t >> 4);
    if (idx >= N) return;
    const int node = perm[idx];

    const int start = offs[node];
    const int end   = start + counts[node];

    const float4 qv = *(const float4*)(q + (size_t)node * D + lane * 4);

    float m = -INFINITY, ssum = 0.0f;
    float4 acc = make_float4(0.0f, 0.0f, 0.0f, 0.0f);

    int j = start;
    for (; j + 2 <= end; j += 2) {
        const int s0 = esrc[j];
        const int s1 = esrc[j + 1];
        const uint4 u0 = kv[(size_t)s0 * 16 + lane];
        const uint4 u1 = kv[(size_t)s1 * 16 + lane];

        float p0 = bflo(u0.x) * qv.x + bfhi(u0.x) * qv.y
                 + bflo(u0.y) * qv.z + bfhi(u0.y) * qv.w;
        float p1 = bflo(u1.x) * qv.x + bfhi(u1.x) * qv.y
                 + bflo(u1.y) * qv.z + bfhi(u1.y) * qv.w;
        p0 += __shfl_xor(p0, 1);  p1 += __shfl_xor(p1, 1);
        p0 += __shfl_xor(p0, 2);  p1 += __shfl_xor(p1, 2);
        p0 += __shfl_xor(p0, 4);  p1 += __shfl_xor(p1, 4);
        p0 += __shfl_xor(p0, 8);  p1 += __shfl_xor(p1, 8);
        p0 *= 0.125f;  p1 *= 0.125f;

        const float mx = fmaxf(p0, p1);
        if (mx > m) {
            const float sc = __expf(m - mx);
            ssum *= sc;
            acc.x *= sc; acc.y *= sc; acc.z *= sc; acc.w *= sc;
            m = mx;
        }
        const float w0 = __expf(p0 - m);
        const float w1 = __expf(p1 - m);
        ssum += w0 + w1;
        acc.x = fmaf(w0, bflo(u0.z), fmaf(w1, bflo(u1.z), acc.x));
        acc.y = fmaf(w0, bfhi(u0.z), fmaf(w1, bfhi(u1.z), acc.y));
        acc.z = fmaf(w0, bflo(u0.w), fmaf(w1, bflo(u1.w), acc.z));
        acc.w = fmaf(w0, bfhi(u0.w), fmaf(w1, bfhi(u1.w), acc.w));
    }
    if (j < end) {
        const int s0 = esrc[j];
        const uint4 u0 = kv[(size_t)s0 * 16 + lane];
        float p0 = bflo(u0.x) * qv.x + bfhi(u0.x) * qv.y
                 + bflo(u0.y) * qv.z + bfhi(u0.y) * qv.w;
        p0 += __shfl_xor(p0, 1);
        p0 += __shfl_xor(p0, 2);
        p0 += __shfl_xor(p0, 4);
        p0 += __shfl_xor(p0, 8);
        p0 *= 0.125f;
        if (p0 > m) {
            const float sc = __expf(m - p0);
            ssum *= sc;
            acc.x *= sc; acc.y *= sc; acc.z *= sc; acc.w *= sc;
            m = p0;
        }
        const float w0 = __expf(p0 - m);
        ssum += w0;
        acc.x = fmaf(w0, bflo(u0.z), acc.x);
        acc.y = fmaf(w0, bfhi(u0.z), acc.y);
        acc.z = fmaf(w0, bflo(u0.w), acc.z);
        acc.w = fmaf(w0, bfhi(u0.w), acc.w);
    }

    const float inv = 1.0f / (ssum + 1e-16f);
    float* o = hout + (size_t)node * D + lane * 4;
    float4 ov = *(const float4*)o;
    ov.x = fmaf(acc.x, inv, ov.x);
    ov.y = fmaf(acc.y, inv, ov.y);
    ov.z = fmaf(acc.z, inv, ov.z);
    ov.w = fmaf(acc.w, inv, ov.w);
    if (do_relu) {
        ov.x = fmaxf(ov.x, 0.0f); ov.y = fmaxf(ov.y, 0.0f);
        ov.z = fmaxf(ov.z, 0.0f); ov.w = fmaxf(ov.w, 0.0f);
    }
    *(float4*)o = ov;
}

extern "C" void kernel_launch(void* const* d_in, const int* in_sizes, int n_in,
                              void* d_out, int out_size, void* d_ws, size_t ws_size,
                              hipStream_t stream)
{
    const float* x   = (const float*)d_in[0];
    const int* ei    = (const int*)d_in[1];
    const float* Wq  = (const float*)d_in[3];
    const float* bq  = (const float*)d_in[4];
    const float* Wk  = (const float*)d_in[5];
    const float* bk  = (const float*)d_in[6];
    const float* Wv  = (const float*)d_in[7];
    const float* bv  = (const float*)d_in[8];
    const float* Ws  = (const float*)d_in[9];
    const float* bs  = (const float*)d_in[10];

    const int N = in_sizes[0] / D;
    const int E = in_sizes[2];
    const int* src = ei;
    const int* dst = ei + E;
    const int NB = (N + 255) / 256;

    // workspace layout
    float* fws = (float*)d_ws;
    float* q     = fws;                             // N*D floats
    ushort_t* kv = (ushort_t*)(q + (size_t)N * D);  // N*128 bf16
    float* h0    = (float*)(kv + (size_t)N * 128);  // N*D
    float* h1    = h0 + (size_t)N * D;              // N*D
    int* esrc    = (int*)(h1 + (size_t)N * D);      // E
    uint2* packed = (uint2*)(esrc + E);             // E uint2
    int* counts  = (int*)(packed + E);              // NBMAX*256
    int* offs    = counts + NBMAX * 256;            // NBMAX*256
    int* bcount  = offs + NBMAX * 256;              // NBMAX
    int* bbase   = bcount + NBMAX;                  // NBMAX+1
    int* gcursor = bbase + NBMAX + 1;               // NBMAX
    int* perm    = gcursor + NBMAX;                 // N
    int* dh      = perm + N;                        // DBINS
    int* dcur    = dh + DBINS;                      // DBINS

    // ---- sort edges by dst + degree-balanced node order (once per call) ----
    hipMemsetAsync(bcount, 0, NBMAX * 4, stream);
    hipMemsetAsync(dh, 0, DBINS * 4, stream);
    const int p1_blocks = (E + CHUNK - 1) / CHUNK;
    b_hist_kernel<<<p1_blocks, 256, 0, stream>>>(dst, bcount, E);
    b_scan_kernel<<<1, NBMAX, 0, stream>>>(bcount, bbase, gcursor, E);
    b_scatter_kernel<<<p1_blocks, 256, 0, stream>>>(src, dst, gcursor, packed, E);
    b_final_kernel<<<NB, 256, 0, stream>>>(packed, bbase, esrc, offs, counts, N);
    deg_hist_kernel<<<(N + 255) / 256, 256, 0, stream>>>(counts, dh, N);
    deg_scan_kernel<<<1, DBINS, 0, stream>>>(dh, dcur);
    deg_scatter_kernel<<<(N + 255) / 256, 256, 0, stream>>>(counts, dcur, perm, N);

    const int proj_blocks = (N + 31) / 32;
    const int node_blocks = (N + 15) / 16;

    const float* cur = x;
    for (int l = 0; l < LAYERS; ++l) {
        float* hout = (l == LAYERS - 1) ? (float*)d_out : (l & 1 ? h1 : h0);

        proj_kernel<<<proj_blocks, 256, 0, stream>>>(
            cur,
            Wq + (size_t)l * D * D, bq + (size_t)l * D,
            Wk + (size_t)l * D * D, bk + (size_t)l * D,
            Wv + (size_t)l * D * D, bv + (size_t)l * D,
            Ws + (size_t)l * D * D, bs + (size_t)l * D,
            q, kv, hout, N);

        node_kernel<<<node_blocks, 256, 0, stream>>>(
            q, (const uint4*)kv, esrc, offs, counts, perm, hout, N,
            l < LAYERS - 1 ? 1 : 0);

        cur = hout;
    }
}

// Round 9
// 359.580 us; speedup vs baseline: 1.8399x; 1.0826x over previous
//
#include <hip/hip_runtime.h>

#define D 64
#define LAYERS 3
#define BSHIFT 8                 // bucket = dst >> 8 (256 nodes per bucket)
#define NBMAX 512                // max buckets supported (N <= 131072)
#define CHUNK 4096               // edges per pass-1 block (256 thr x 16)
#define WSTRIDE 72               // padded LDS row stride (ushorts)

typedef unsigned short ushort_t;
typedef __bf16 bf16x8 __attribute__((ext_vector_type(8)));
typedef float f32x4 __attribute__((ext_vector_type(4)));

__device__ __forceinline__ ushort_t f2bf(float f) {           // RNE float->bf16
    unsigned b = __float_as_uint(f);
    b += 0x7FFFu + ((b >> 16) & 1u);
    return (ushort_t)(b >> 16);
}
__device__ __forceinline__ float bflo(unsigned u) { return __uint_as_float(u << 16); }
__device__ __forceinline__ float bfhi(unsigned u) { return __uint_as_float(u & 0xFFFF0000u); }

// ---------------- projections via MFMA ----------------
// Per block: 32 rows. Wave w computes x@W[w]: 0=q, 1=k, 2=v, 3=skip.
// q -> bf16 qb[N][64]; skip -> bf16 sk[N][64]; k,v -> packed bf16 kv[N][128]
// (chunk g: [g*8..g*8+3]=k cols 4g..4g+3, [g*8+4..g*8+7]=v cols).
__global__ __launch_bounds__(256) void proj_kernel(
    const float* __restrict__ x,
    const float* __restrict__ Wq, const float* __restrict__ bq,
    const float* __restrict__ Wk, const float* __restrict__ bk,
    const float* __restrict__ Wv, const float* __restrict__ bv,
    const float* __restrict__ Ws, const float* __restrict__ bs,
    ushort_t* __restrict__ qb, ushort_t* __restrict__ kv,
    ushort_t* __restrict__ sk, int N)
{
    __shared__ ushort_t xs[32 * WSTRIDE];
    __shared__ ushort_t wt[4 * 64 * WSTRIDE];

    const int t = threadIdx.x;
    const int block_row = blockIdx.x * 32;

    {   // stage x tile (fp32 -> bf16)
        const int r  = t >> 3;
        const int c8 = (t & 7) * 8;
        const int row = block_row + r;
        float4 x0, x1;
        if (row < N) {
            x0 = *(const float4*)(x + (size_t)row * D + c8);
            x1 = *(const float4*)(x + (size_t)row * D + c8 + 4);
        } else {
            x0 = make_float4(0.f,0.f,0.f,0.f); x1 = x0;
        }
        uint4 u;
        u.x = (unsigned)f2bf(x0.x) | ((unsigned)f2bf(x0.y) << 16);
        u.y = (unsigned)f2bf(x0.z) | ((unsigned)f2bf(x0.w) << 16);
        u.z = (unsigned)f2bf(x1.x) | ((unsigned)f2bf(x1.y) << 16);
        u.w = (unsigned)f2bf(x1.z) | ((unsigned)f2bf(x1.w) << 16);
        *(uint4*)(xs + r * WSTRIDE + c8) = u;
    }
    {   // stage W^T (fp32 -> bf16): wt[m][n*WSTRIDE+k] = W_m[k*64+n]
        const float* Wm[4] = {Wq, Wk, Wv, Ws};
#pragma unroll
        for (int m = 0; m < 4; ++m) {
            const float* W = Wm[m];
            ushort_t* wtm = wt + m * 64 * WSTRIDE;
#pragma unroll
            for (int i = 0; i < 16; ++i) {
                const int e = i * 256 + t;
                const int k = e >> 6, n = e & 63;
                wtm[n * WSTRIDE + k] = f2bf(W[e]);
            }
        }
    }
    __syncthreads();

    const int l  = t & 63;
    const int w  = t >> 6;            // wave id: 0=q,1=k,2=v,3=skip
    const int lr = l & 15;
    const int lk = (l >> 4) * 8;

    bf16x8 afr[2][2];
#pragma unroll
    for (int rt = 0; rt < 2; ++rt)
#pragma unroll
        for (int ks = 0; ks < 2; ++ks)
            afr[rt][ks] = *(const bf16x8*)(xs + (rt*16 + lr) * WSTRIDE + ks*32 + lk);

    const ushort_t* wtw = wt + w * 64 * WSTRIDE;
    f32x4 acc[2][4];
#pragma unroll
    for (int rt = 0; rt < 2; ++rt)
#pragma unroll
        for (int ct = 0; ct < 4; ++ct)
            acc[rt][ct] = (f32x4){0.f, 0.f, 0.f, 0.f};

#pragma unroll
    for (int ct = 0; ct < 4; ++ct) {
        const bf16x8 b0 = *(const bf16x8*)(wtw + (ct*16 + lr) * WSTRIDE + lk);
        const bf16x8 b1 = *(const bf16x8*)(wtw + (ct*16 + lr) * WSTRIDE + 32 + lk);
        acc[0][ct] = __builtin_amdgcn_mfma_f32_16x16x32_bf16(afr[0][0], b0, acc[0][ct], 0, 0, 0);
        acc[0][ct] = __builtin_amdgcn_mfma_f32_16x16x32_bf16(afr[0][1], b1, acc[0][ct], 0, 0, 0);
        acc[1][ct] = __builtin_amdgcn_mfma_f32_16x16x32_bf16(afr[1][0], b0, acc[1][ct], 0, 0, 0);
        acc[1][ct] = __builtin_amdgcn_mfma_f32_16x16x32_bf16(afr[1][1], b1, acc[1][ct], 0, 0, 0);
    }

    const float* biasW = (w == 0) ? bq : (w == 1) ? bk : (w == 2) ? bv : bs;
    float bcol[4];
#pragma unroll
    for (int ct = 0; ct < 4; ++ct) bcol[ct] = biasW[ct*16 + lr];

#pragma unroll
    for (int rt = 0; rt < 2; ++rt) {
#pragma unroll
        for (int ct = 0; ct < 4; ++ct) {
#pragma unroll
            for (int r = 0; r < 4; ++r) {
                const int row = block_row + rt*16 + (l >> 4) * 4 + r;
                const int col = ct*16 + lr;
                if (row < N) {
                    const float val = acc[rt][ct][r] + bcol[ct];
                    if (w == 0)      qb[(size_t)row * D + col] = f2bf(val);
                    else if (w == 3) sk[(size_t)row * D + col] = f2bf(val);
                    else {
                        ushort_t* kvr = kv + (size_t)row * 128;
                        kvr[(col >> 2) * 8 + ((w == 2) ? 4 : 0) + (col & 3)] = f2bf(val);
                    }
                }
            }
        }
    }
}

// ---------------- two-pass bucketed counting sort ----------------
__global__ __launch_bounds__(256) void b_hist_kernel(
    const int* __restrict__ dst, int* __restrict__ bcount, int E)
{
    __shared__ int h[NBMAX];
    const int t = threadIdx.x;
    h[t] = 0; h[t + 256] = 0;
    __syncthreads();
    const int base = blockIdx.x * CHUNK;
#pragma unroll
    for (int i = 0; i < 16; ++i) {
        const int e = base + i * 256 + t;
        if (e < E) atomicAdd(h + (dst[e] >> BSHIFT), 1);
    }
    __syncthreads();
    if (h[t])       atomicAdd(bcount + t, h[t]);
    if (h[t + 256]) atomicAdd(bcount + t + 256, h[t + 256]);
}

__global__ __launch_bounds__(512) void b_scan_kernel(
    const int* __restrict__ bcount, int* __restrict__ bbase,
    int* __restrict__ gcursor, int E)
{
    __shared__ int tmp[NBMAX];
    const int t = threadIdx.x;
    const int val = bcount[t];
    tmp[t] = val;
    __syncthreads();
    for (int off = 1; off < NBMAX; off <<= 1) {
        int x = (t >= off) ? tmp[t - off] : 0;
        __syncthreads();
        tmp[t] += x;
        __syncthreads();
    }
    const int excl = tmp[t] - val;
    bbase[t] = excl;
    gcursor[t] = excl;
    if (t == NBMAX - 1) bbase[NBMAX] = E;
}

__global__ __launch_bounds__(256) void b_scatter_kernel(
    const int* __restrict__ src, const int* __restrict__ dst,
    int* __restrict__ gcursor, uint2* __restrict__ packed, int E)
{
    __shared__ int h[NBMAX];
    __shared__ int gb[NBMAX];
    const int t = threadIdx.x;
    h[t] = 0; h[t + 256] = 0;
    __syncthreads();

    const int base = blockIdx.x * CHUNK;
    int ls[16], ld[16], lr[16];
#pragma unroll
    for (int i = 0; i < 16; ++i) {
        const int e = base + i * 256 + t;
        if (e < E) {
            ls[i] = src[e];
            ld[i] = dst[e];
            lr[i] = atomicAdd(h + (ld[i] >> BSHIFT), 1);
        }
    }
    __syncthreads();
    for (int b = t; b < NBMAX; b += 256) {
        const int c = h[b];
        gb[b] = c ? atomicAdd(gcursor + b, c) : 0;
    }
    __syncthreads();
#pragma unroll
    for (int i = 0; i < 16; ++i) {
        const int e = base + i * 256 + t;
        if (e < E) {
            const int pos = gb[ld[i] >> BSHIFT] + lr[i];
            packed[pos] = make_uint2((unsigned)ls[i], (unsigned)ld[i]);
        }
    }
}

__global__ __launch_bounds__(256) void b_final_kernel(
    const uint2* __restrict__ packed, const int* __restrict__ bbase,
    int* __restrict__ esrc, int* __restrict__ offs, int* __restrict__ counts,
    int N)
{
    __shared__ int hist[256];
    __shared__ int scan[256];
    __shared__ int cursor[256];
    const int t = threadIdx.x;
    const int b = blockIdx.x;
    const int s = bbase[b];
    const int e = bbase[b + 1];

    hist[t] = 0;
    __syncthreads();
    for (int j = s + t; j < e; j += 256) {
        atomicAdd(hist + (packed[j].y & 255), 1);
    }
    __syncthreads();
    const int val = hist[t];
    scan[t] = val;
    __syncthreads();
    for (int off = 1; off < 256; off <<= 1) {
        int x = (t >= off) ? scan[t - off] : 0;
        __syncthreads();
        scan[t] += x;
        __syncthreads();
    }
    const int excl = scan[t] - val;
    const int node = b * 256 + t;
    if (node < N) {
        counts[node] = val;
        offs[node]   = s + excl;
    }
    cursor[t] = excl;
    __syncthreads();
    for (int j = s + t; j < e; j += 256) {
        const uint2 p = packed[j];
        const int r = atomicAdd(cursor + (p.y & 255), 1);
        esrc[s + r] = (int)p.x;
    }
}

// ---------------- fused per-node attention ----------------
// 16 lanes/node, dst-sorted edges, online softmax. Reads q/skip bf16,
// writes hout fp32 (write-only, no RMW).
__global__ __launch_bounds__(256) void node_kernel(
    const ushort_t* __restrict__ qb, const uint4* __restrict__ kv,
    const int* __restrict__ esrc, const int* __restrict__ offs,
    const int* __restrict__ counts, const ushort_t* __restrict__ sk,
    float* __restrict__ hout, int N, int do_relu)
{
    const int t = threadIdx.x;
    const int lane = t & 15;
    const int node = blockIdx.x * 16 + (t >> 4);
    if (node >= N) return;

    const int start = offs[node];
    const int end   = start + counts[node];

    const uint2 qu = *(const uint2*)(qb + (size_t)node * D + lane * 4);
    float4 qv;
    qv.x = bflo(qu.x); qv.y = bfhi(qu.x);
    qv.z = bflo(qu.y); qv.w = bfhi(qu.y);

    float m = -INFINITY, ssum = 0.0f;
    float4 acc = make_float4(0.0f, 0.0f, 0.0f, 0.0f);

    int j = start;
    for (; j + 2 <= end; j += 2) {
        const int s0 = esrc[j];
        const int s1 = esrc[j + 1];
        const uint4 u0 = kv[(size_t)s0 * 16 + lane];
        const uint4 u1 = kv[(size_t)s1 * 16 + lane];

        float p0 = bflo(u0.x) * qv.x + bfhi(u0.x) * qv.y
                 + bflo(u0.y) * qv.z + bfhi(u0.y) * qv.w;
        float p1 = bflo(u1.x) * qv.x + bfhi(u1.x) * qv.y
                 + bflo(u1.y) * qv.z + bfhi(u1.y) * qv.w;
        p0 += __shfl_xor(p0, 1);  p1 += __shfl_xor(p1, 1);
        p0 += __shfl_xor(p0, 2);  p1 += __shfl_xor(p1, 2);
        p0 += __shfl_xor(p0, 4);  p1 += __shfl_xor(p1, 4);
        p0 += __shfl_xor(p0, 8);  p1 += __shfl_xor(p1, 8);
        p0 *= 0.125f;  p1 *= 0.125f;

        const float mx = fmaxf(p0, p1);
        if (mx > m) {
            const float sc = __expf(m - mx);
            ssum *= sc;
            acc.x *= sc; acc.y *= sc; acc.z *= sc; acc.w *= sc;
            m = mx;
        }
        const float w0 = __expf(p0 - m);
        const float w1 = __expf(p1 - m);
        ssum += w0 + w1;
        acc.x = fmaf(w0, bflo(u0.z), fmaf(w1, bflo(u1.z), acc.x));
        acc.y = fmaf(w0, bfhi(u0.z), fmaf(w1, bfhi(u1.z), acc.y));
        acc.z = fmaf(w0, bflo(u0.w), fmaf(w1, bflo(u1.w), acc.z));
        acc.w = fmaf(w0, bfhi(u0.w), fmaf(w1, bfhi(u1.w), acc.w));
    }
    if (j < end) {
        const int s0 = esrc[j];
        const uint4 u0 = kv[(size_t)s0 * 16 + lane];
        float p0 = bflo(u0.x) * qv.x + bfhi(u0.x) * qv.y
                 + bflo(u0.y) * qv.z + bfhi(u0.y) * qv.w;
        p0 += __shfl_xor(p0, 1);
        p0 += __shfl_xor(p0, 2);
        p0 += __shfl_xor(p0, 4);
        p0 += __shfl_xor(p0, 8);
        p0 *= 0.125f;
        if (p0 > m) {
            const float sc = __expf(m - p0);
            ssum *= sc;
            acc.x *= sc; acc.y *= sc; acc.z *= sc; acc.w *= sc;
            m = p0;
        }
        const float w0 = __expf(p0 - m);
        ssum += w0;
        acc.x = fmaf(w0, bflo(u0.z), acc.x);
        acc.y = fmaf(w0, bfhi(u0.z), acc.y);
        acc.z = fmaf(w0, bflo(u0.w), acc.z);
        acc.w = fmaf(w0, bfhi(u0.w), acc.w);
    }

    const float inv = 1.0f / (ssum + 1e-16f);
    const uint2 su = *(const uint2*)(sk + (size_t)node * D + lane * 4);
    float4 ov;
    ov.x = fmaf(acc.x, inv, bflo(su.x));
    ov.y = fmaf(acc.y, inv, bfhi(su.x));
    ov.z = fmaf(acc.z, inv, bflo(su.y));
    ov.w = fmaf(acc.w, inv, bfhi(su.y));
    if (do_relu) {
        ov.x = fmaxf(ov.x, 0.0f); ov.y = fmaxf(ov.y, 0.0f);
        ov.z = fmaxf(ov.z, 0.0f); ov.w = fmaxf(ov.w, 0.0f);
    }
    *(float4*)(hout + (size_t)node * D + lane * 4) = ov;
}

extern "C" void kernel_launch(void* const* d_in, const int* in_sizes, int n_in,
                              void* d_out, int out_size, void* d_ws, size_t ws_size,
                              hipStream_t stream)
{
    const float* x   = (const float*)d_in[0];
    const int* ei    = (const int*)d_in[1];
    const float* Wq  = (const float*)d_in[3];
    const float* bq  = (const float*)d_in[4];
    const float* Wk  = (const float*)d_in[5];
    const float* bk  = (const float*)d_in[6];
    const float* Wv  = (const float*)d_in[7];
    const float* bv  = (const float*)d_in[8];
    const float* Ws  = (const float*)d_in[9];
    const float* bs  = (const float*)d_in[10];

    const int N = in_sizes[0] / D;
    const int E = in_sizes[2];
    const int* src = ei;
    const int* dst = ei + E;
    const int NB = (N + 255) / 256;

    // workspace layout
    ushort_t* qb = (ushort_t*)d_ws;                 // N*64 bf16
    ushort_t* kv = qb + (size_t)N * D;              // N*128 bf16
    ushort_t* sk = kv + (size_t)N * 128;            // N*64 bf16
    float* h0    = (float*)(sk + (size_t)N * D);    // N*D fp32
    float* h1    = h0 + (size_t)N * D;              // N*D fp32
    int* esrc    = (int*)(h1 + (size_t)N * D);      // E
    uint2* packed = (uint2*)(esrc + E);             // E uint2
    int* counts  = (int*)(packed + E);              // NBMAX*256
    int* offs    = counts + NBMAX * 256;            // NBMAX*256
    int* bcount  = offs + NBMAX * 256;              // NBMAX
    int* bbase   = bcount + NBMAX;                  // NBMAX+1
    int* gcursor = bbase + NBMAX + 1;               // NBMAX

    // ---- sort edges by dst (once per call; reused across layers) ----
    hipMemsetAsync(bcount, 0, NBMAX * 4, stream);
    const int p1_blocks = (E + CHUNK - 1) / CHUNK;
    b_hist_kernel<<<p1_blocks, 256, 0, stream>>>(dst, bcount, E);
    b_scan_kernel<<<1, NBMAX, 0, stream>>>(bcount, bbase, gcursor, E);
    b_scatter_kernel<<<p1_blocks, 256, 0, stream>>>(src, dst, gcursor, packed, E);
    b_final_kernel<<<NB, 256, 0, stream>>>(packed, bbase, esrc, offs, counts, N);

    const int proj_blocks = (N + 31) / 32;
    const int node_blocks = (N + 15) / 16;

    const float* cur = x;
    for (int l = 0; l < LAYERS; ++l) {
        float* hout = (l == LAYERS - 1) ? (float*)d_out : (l & 1 ? h1 : h0);

        proj_kernel<<<proj_blocks, 256, 0, stream>>>(
            cur,
            Wq + (size_t)l * D * D, bq + (size_t)l * D,
            Wk + (size_t)l * D * D, bk + (size_t)l * D,
            Wv + (size_t)l * D * D, bv + (size_t)l * D,
            Ws + (size_t)l * D * D, bs + (size_t)l * D,
            qb, kv, sk, N);

        node_kernel<<<node_blocks, 256, 0, stream>>>(
            qb, (const uint4*)kv, esrc, offs, counts, sk, hout, N,
            l < LAYERS - 1 ? 1 : 0);

        cur = hout;
    }
}